// Round 1
// baseline (333.819 us; speedup 1.0000x reference)
//
#include <hip/hip_runtime.h>

// TemporalBasis: T=512, H=8, BATCH=4, N=4096, B=4; sites S = BATCH*N = 16384.
// z_{t+1} = d*z_t + s_t (per site, per basis k), resp[t][h] = dot(coeffs[h], z_{t+1}).
//
// Two-kernel chunked scan:
//  K1 (tb_scan): per (chunk,site) compute chunk-local partial P_k = sum_j d^(L-1-j) s_j
//     and packed spike bitmask; prefix-combine prior chunks in LDS -> chunk-start
//     spike-driven state A; write A (4 MB) + masks (1 MB) to workspace.
//  K2 (tb_replay): block = ONE chunk x 1024 consecutive sites (16 waves, same chunk).
//     Replay 32 steps from A + bitmask, emitting 8 head responses/step. Per step the
//     block writes 8 contiguous 4 KB bursts (vs 256 B bursts in the fused kernel) --
//     site-major write locality is the whole point of the split.
#define HH 8
#define BB 4
#define TT 512
#define CHUNKS 16
#define LL (TT / CHUNKS)   // 32
#define SPB 64             // sites per block in scan kernel (one wave per chunk)
#define K2T 1024           // threads (= consecutive sites) per replay block

// ---------------- Kernel 1: chunk-local scan + prefix combine ----------------
__global__ __launch_bounds__(CHUNKS * SPB)
void tb_scan(const float* __restrict__ spikes,
             const float* __restrict__ taus,
             const int* __restrict__ dt_p,
             float4* __restrict__ Abuf,          // [CHUNKS][S] chunk-start spike states
             unsigned int* __restrict__ Mbuf,    // [CHUNKS][S] packed spike bitmasks
             int S) {
    __shared__ float4 lds_P[CHUNKS][SPB];

    const int chunk = threadIdx.x >> 6;          // wave id == chunk id
    const int sl    = threadIdx.x & 63;
    const int site  = blockIdx.x * SPB + sl;

    const float dt = (float)dt_p[0];
    float d[BB];
#pragma unroll
    for (int k = 0; k < BB; ++k) d[k] = expf(-dt / taus[k]);

    const int t0 = chunk * LL;
    float P[BB] = {0.f, 0.f, 0.f, 0.f};
    unsigned mask = 0u;
    const float* __restrict__ sp = spikes + (size_t)t0 * S + site;
#pragma unroll
    for (int i = 0; i < LL; ++i) {
        const float s = sp[(size_t)i * S];
        mask |= (s != 0.f ? 1u : 0u) << i;
#pragma unroll
        for (int k = 0; k < BB; ++k) P[k] = d[k] * P[k] + s;
    }
    Mbuf[(size_t)chunk * S + site] = mask;
    lds_P[chunk][sl] = make_float4(P[0], P[1], P[2], P[3]);
    __syncthreads();

    // d^L via 5 squarings (L = 32) -- numerics identical to fused kernel
    float dL[BB];
#pragma unroll
    for (int k = 0; k < BB; ++k) {
        float x = d[k];
        x = x * x; x = x * x; x = x * x; x = x * x; x = x * x;
        dL[k] = x;
    }

    float A[BB] = {0.f, 0.f, 0.f, 0.f};
    for (int e = 0; e < chunk; ++e) {
        const float4 p = lds_P[e][sl];
        A[0] = dL[0] * A[0] + p.x;
        A[1] = dL[1] * A[1] + p.y;
        A[2] = dL[2] * A[2] + p.z;
        A[3] = dL[3] * A[3] + p.w;
    }
    Abuf[(size_t)chunk * S + site] = make_float4(A[0], A[1], A[2], A[3]);
}

// ---------------- Kernel 2: site-major replay ----------------
__global__ __launch_bounds__(K2T)
void tb_replay(const float* __restrict__ z0,
               const float* __restrict__ taus,
               const float* __restrict__ coeffs,
               const int* __restrict__ dt_p,
               const float4* __restrict__ Abuf,
               const unsigned int* __restrict__ Mbuf,
               float* __restrict__ out,
               int S) {
    const int nsb   = S / K2T;                   // site-blocks per chunk (16)
    const int chunk = blockIdx.x / nsb;          // consecutive bids share a t-plane
    const int sb    = blockIdx.x - chunk * nsb;
    const int site  = sb * K2T + threadIdx.x;
    const int t0    = chunk * LL;

    const float dt = (float)dt_p[0];
    float d[BB];
#pragma unroll
    for (int k = 0; k < BB; ++k) d[k] = expf(-dt / taus[k]);

    // d^L via 5 squarings, d^(t0) = (d^L)^chunk -- same numerics as before
    float dL[BB];
#pragma unroll
    for (int k = 0; k < BB; ++k) {
        float x = d[k];
        x = x * x; x = x * x; x = x * x; x = x * x; x = x * x;
        dL[k] = x;
    }
    float dt0[BB] = {1.f, 1.f, 1.f, 1.f};
    for (int e = 0; e < chunk; ++e) {
#pragma unroll
        for (int k = 0; k < BB; ++k) dt0[k] *= dL[k];
    }

    const float4 Av = Abuf[(size_t)chunk * S + site];
    unsigned mask = Mbuf[(size_t)chunk * S + site];

    // init z[h][k] = d^(t0) * z0[h][k] + A[k]
    float z[HH][BB];
#pragma unroll
    for (int h = 0; h < HH; ++h) {
        const float4 zv = ((const float4*)z0)[(size_t)h * S + site];
        z[h][0] = dt0[0] * zv.x + Av.x;
        z[h][1] = dt0[1] * zv.y + Av.y;
        z[h][2] = dt0[2] * zv.z + Av.z;
        z[h][3] = dt0[3] * zv.w + Av.w;
    }

    // mixing coefficients (uniform address -> scalar loads)
    float c[HH][BB];
#pragma unroll
    for (int h = 0; h < HH; ++h)
#pragma unroll
        for (int k = 0; k < BB; ++k) c[h][k] = coeffs[h * BB + k];

    // replay: no global loads, stores only. Block writes 8 x 4 KB bursts per step.
    float* __restrict__ op = out + (size_t)t0 * HH * S + site;
#pragma unroll 4
    for (int i = 0; i < LL; ++i) {
        const float s = (mask & (1u << i)) ? 1.0f : 0.0f;
#pragma unroll
        for (int h = 0; h < HH; ++h) {
#pragma unroll
            for (int k = 0; k < BB; ++k) z[h][k] = d[k] * z[h][k] + s;
            const float r = z[h][0] * c[h][0] + z[h][1] * c[h][1] +
                            z[h][2] * c[h][2] + z[h][3] * c[h][3];
            __builtin_nontemporal_store(r, &op[(size_t)(i * HH + h) * S]);
        }
    }
}

// ---------------- Fallback: previous fused kernel (ws too small) ----------------
__global__ __launch_bounds__(CHUNKS * SPB)
void temporal_basis_kernel(const float* __restrict__ z0,
                           const float* __restrict__ spikes,
                           const float* __restrict__ taus,
                           const float* __restrict__ coeffs,
                           const int* __restrict__ dt_p,
                           float* __restrict__ out,
                           int S) {
    __shared__ float4 lds_P[CHUNKS][SPB];

    const int chunk = threadIdx.x >> 6;
    const int sl    = threadIdx.x & 63;
    const int site  = blockIdx.x * SPB + sl;

    const float dt = (float)dt_p[0];
    float d[BB];
#pragma unroll
    for (int k = 0; k < BB; ++k) d[k] = expf(-dt / taus[k]);

    const int t0 = chunk * LL;
    float P[BB] = {0.f, 0.f, 0.f, 0.f};
    unsigned mask = 0u;
    const float* __restrict__ sp = spikes + (size_t)t0 * S + site;
#pragma unroll
    for (int i = 0; i < LL; ++i) {
        const float s = sp[(size_t)i * S];
        mask |= (s != 0.f ? 1u : 0u) << i;
#pragma unroll
        for (int k = 0; k < BB; ++k) P[k] = d[k] * P[k] + s;
    }
    lds_P[chunk][sl] = make_float4(P[0], P[1], P[2], P[3]);
    __syncthreads();

    float dL[BB];
#pragma unroll
    for (int k = 0; k < BB; ++k) {
        float x = d[k];
        x = x * x; x = x * x; x = x * x; x = x * x; x = x * x;
        dL[k] = x;
    }

    float A[BB] = {0.f, 0.f, 0.f, 0.f};
    for (int e = 0; e < chunk; ++e) {
        const float4 p = lds_P[e][sl];
        A[0] = dL[0] * A[0] + p.x;
        A[1] = dL[1] * A[1] + p.y;
        A[2] = dL[2] * A[2] + p.z;
        A[3] = dL[3] * A[3] + p.w;
    }

    float dt0[BB] = {1.f, 1.f, 1.f, 1.f};
    for (int e = 0; e < chunk; ++e) {
#pragma unroll
        for (int k = 0; k < BB; ++k) dt0[k] *= dL[k];
    }

    float z[HH][BB];
#pragma unroll
    for (int h = 0; h < HH; ++h) {
        const float4 zv = ((const float4*)z0)[(size_t)h * S + site];
        z[h][0] = dt0[0] * zv.x + A[0];
        z[h][1] = dt0[1] * zv.y + A[1];
        z[h][2] = dt0[2] * zv.z + A[2];
        z[h][3] = dt0[3] * zv.w + A[3];
    }

    float c[HH][BB];
#pragma unroll
    for (int h = 0; h < HH; ++h)
#pragma unroll
        for (int k = 0; k < BB; ++k) c[h][k] = coeffs[h * BB + k];

    float* __restrict__ op = out + (size_t)t0 * HH * S + site;
#pragma unroll 4
    for (int i = 0; i < LL; ++i) {
        const float s = (mask & (1u << i)) ? 1.0f : 0.0f;
#pragma unroll
        for (int h = 0; h < HH; ++h) {
#pragma unroll
            for (int k = 0; k < BB; ++k) z[h][k] = d[k] * z[h][k] + s;
            const float r = z[h][0] * c[h][0] + z[h][1] * c[h][1] +
                            z[h][2] * c[h][2] + z[h][3] * c[h][3];
            __builtin_nontemporal_store(r, &op[(size_t)(i * HH + h) * S]);
        }
    }
}

extern "C" void kernel_launch(void* const* d_in, const int* in_sizes, int n_in,
                              void* d_out, int out_size, void* d_ws, size_t ws_size,
                              hipStream_t stream) {
    const float* z0     = (const float*)d_in[0];
    const float* spikes = (const float*)d_in[1];
    const float* taus   = (const float*)d_in[2];
    const float* coeffs = (const float*)d_in[3];
    const int*   dt_p   = (const int*)d_in[4];
    float* out = (float*)d_out;

    const int S = in_sizes[1] / TT;   // 16384 sites

    const size_t abytes = (size_t)CHUNKS * S * sizeof(float4);   // 4 MB
    const size_t mbytes = (size_t)CHUNKS * S * sizeof(unsigned); // 1 MB

    if (d_ws != nullptr && ws_size >= abytes + mbytes) {
        float4* Abuf       = (float4*)d_ws;
        unsigned int* Mbuf = (unsigned int*)((char*)d_ws + abytes);

        tb_scan<<<S / SPB, CHUNKS * SPB, 0, stream>>>(
            spikes, taus, dt_p, Abuf, Mbuf, S);

        const int grid2 = CHUNKS * (S / K2T);    // 256 blocks
        tb_replay<<<grid2, K2T, 0, stream>>>(
            z0, taus, coeffs, dt_p, Abuf, Mbuf, out, S);
    } else {
        temporal_basis_kernel<<<S / SPB, CHUNKS * SPB, 0, stream>>>(
            z0, spikes, taus, coeffs, dt_p, out, S);
    }
}

// Round 2
// 302.393 us; speedup vs baseline: 1.1039x; 1.1039x over previous
//
#include <hip/hip_runtime.h>

// TemporalBasis: T=512, H=8, BATCH=4, N=4096, B=4; sites S = BATCH*N = 16384.
// z_{t+1} = d*z_t + s_t (per site, per basis k), resp[t][h] = dot(coeffs[h], z_{t+1}).
//
// Chunked-scan decomposition: 16 chunks x 32 steps per block of 64 sites.
// Phase 1: each (chunk,site) thread computes chunk-local partials
//   P_k = sum_j d_k^(L-1-j) s_j  -> LDS, and packs the 32 binary spikes into a
//   uint32 bitmask (spikes are exactly 0.0/1.0) so the replay loop needs NO
//   global loads.
// Phase 2: prefix-combine prior chunks' P from LDS -> chunk-start state, then
//   replay 32 steps emitting 8 head responses per step.
//
// R2 change vs R0 baseline: PLAIN stores instead of __builtin_nontemporal_store.
// R1 showed write-burst size is not the limiter (4 KB bursts == 256 B bursts);
// the fill kernel reaches 6.5 TB/s with plain stores while our nt stores sit at
// ~3.2 TB/s effective -> let L2 aggregate the write-once output stream.
#define HH 8
#define BB 4
#define TT 512
#define CHUNKS 16
#define LL (TT / CHUNKS)   // 32
#define SPB 64             // sites per block (one wave per chunk)

__global__ __launch_bounds__(CHUNKS * SPB)
void temporal_basis_kernel(const float* __restrict__ z0,
                           const float* __restrict__ spikes,
                           const float* __restrict__ taus,
                           const float* __restrict__ coeffs,
                           const int* __restrict__ dt_p,
                           float* __restrict__ out,
                           int S) {
    __shared__ float4 lds_P[CHUNKS][SPB];

    const int chunk = threadIdx.x >> 6;           // wave id == chunk id
    const int sl    = threadIdx.x & 63;
    const int site  = blockIdx.x * SPB + sl;

    // decay factors d_k = exp(-dt / tau_k)
    const float dt = (float)dt_p[0];
    float d[BB];
#pragma unroll
    for (int k = 0; k < BB; ++k) d[k] = expf(-dt / taus[k]);

    // ---- Phase 1: chunk-local partial sums + spike bitmask ----
    const int t0 = chunk * LL;
    float P[BB] = {0.f, 0.f, 0.f, 0.f};
    unsigned mask = 0u;
    const float* __restrict__ sp = spikes + (size_t)t0 * S + site;
#pragma unroll
    for (int i = 0; i < LL; ++i) {
        const float s = sp[(size_t)i * S];
        mask |= (s != 0.f ? 1u : 0u) << i;
#pragma unroll
        for (int k = 0; k < BB; ++k) P[k] = d[k] * P[k] + s;
    }
    lds_P[chunk][sl] = make_float4(P[0], P[1], P[2], P[3]);
    __syncthreads();

    // d^L via 5 squarings (L = 32)
    float dL[BB];
#pragma unroll
    for (int k = 0; k < BB; ++k) {
        float x = d[k];
        x = x * x; x = x * x; x = x * x; x = x * x; x = x * x;
        dL[k] = x;
    }

    // ---- Phase 2: combine prior chunks -> spike-driven state at t0 ----
    float A[BB] = {0.f, 0.f, 0.f, 0.f};
    for (int e = 0; e < chunk; ++e) {
        const float4 p = lds_P[e][sl];
        A[0] = dL[0] * A[0] + p.x;
        A[1] = dL[1] * A[1] + p.y;
        A[2] = dL[2] * A[2] + p.z;
        A[3] = dL[3] * A[3] + p.w;
    }

    // d^(t0) = (d^L)^chunk
    float dt0[BB] = {1.f, 1.f, 1.f, 1.f};
    for (int e = 0; e < chunk; ++e) {
#pragma unroll
        for (int k = 0; k < BB; ++k) dt0[k] *= dL[k];
    }

    // init z[h][k] = d^(t0) * z0[h][k] + A[k]
    float z[HH][BB];
#pragma unroll
    for (int h = 0; h < HH; ++h) {
        const float4 zv = ((const float4*)z0)[(size_t)h * S + site];
        z[h][0] = dt0[0] * zv.x + A[0];
        z[h][1] = dt0[1] * zv.y + A[1];
        z[h][2] = dt0[2] * zv.z + A[2];
        z[h][3] = dt0[3] * zv.w + A[3];
    }

    // mixing coefficients (wave-uniform -> compiler keeps in SGPRs)
    float c[HH][BB];
#pragma unroll
    for (int h = 0; h < HH; ++h)
#pragma unroll
        for (int k = 0; k < BB; ++k) c[h][k] = coeffs[h * BB + k];

    // ---- replay loop: no global loads, stores only (plain stores -> L2) ----
    float* __restrict__ op = out + (size_t)t0 * HH * S + site;
#pragma unroll 4
    for (int i = 0; i < LL; ++i) {
        const float s = (mask & (1u << i)) ? 1.0f : 0.0f;
#pragma unroll
        for (int h = 0; h < HH; ++h) {
#pragma unroll
            for (int k = 0; k < BB; ++k) z[h][k] = d[k] * z[h][k] + s;
            const float r = z[h][0] * c[h][0] + z[h][1] * c[h][1] +
                            z[h][2] * c[h][2] + z[h][3] * c[h][3];
            op[(size_t)(i * HH + h) * S] = r;
        }
    }
}

extern "C" void kernel_launch(void* const* d_in, const int* in_sizes, int n_in,
                              void* d_out, int out_size, void* d_ws, size_t ws_size,
                              hipStream_t stream) {
    const float* z0     = (const float*)d_in[0];
    const float* spikes = (const float*)d_in[1];
    const float* taus   = (const float*)d_in[2];
    const float* coeffs = (const float*)d_in[3];
    const int*   dt_p   = (const int*)d_in[4];
    float* out = (float*)d_out;

    const int S = in_sizes[1] / TT;   // 16384 sites
    const int grid = S / SPB;         // 256 blocks

    temporal_basis_kernel<<<grid, CHUNKS * SPB, 0, stream>>>(
        z0, spikes, taus, coeffs, dt_p, out, S);
}